// Round 12
// baseline (94.330 us; speedup 1.0000x reference)
//
#include <hip/hip_runtime.h>

// ---------------------------------------------------------------------------
// TaskAlignedAssigner (YOLO TAL) for MI355X — 2 dispatches, no column pass.
// B=32, A=8400, M=32, C=80 (derived at runtime; M<=32 so a gt-column mask
// fits one uint32 per anchor; C%4==0 assumed for float4 ts writes).
//
// Outputs (concatenated float32, return order):
//   tl (B,A) | tb (B,A,4) | ts (B,A,C) | fg (B,A) | tgt (B,A)
//
// R1:  removed global atomic histogram (65us same-cacheline serialization).
// R2:  fix2 wave-parallel register scan (was 71.7us dependent-latency).
// R3  (regressed): select1 inside 32-block fix2 -> 32/256 CUs busy.
// R4:  select1 full-grid; 5 kernels + memset = 74.5us.
// R5  (regressed, 250us): cooperative kernel — grid.sync ~60-70us each.
// R6  (regressed, 127us): ticket+__threadfence — ~90us of L2 writeback.
// R7:  4 dispatches, no fences: 59.9us.
// R8:  2 dispatches (columns+chunks merged; override-list k_final): 53.3us.
// R9  (regressed, 91us): per-chunk column reduce -> v[32] scratch spill.
// R10: R8 phase1 + light main pass (tgt=tgt0 unless overridden): 51.7us.
// R11: column tasks DELETED. colKey is only consumed for columns with
//      cnt0 <= M (fix2 can't drain >M counts: <=M steps x 1 decrement) or
//      !hasin (fix1). k_final's prologue computes the flagged set and runs
//      the A-scan argmax only for those columns (typically 0-3) with all
//      256 threads, colKey in LDS. phase1 = chunk tasks only (+hasinChunk
//      OR-word). Saves 1024 blocks and ~137MB of L2 re-reads per launch.
// ---------------------------------------------------------------------------

#define EPS_IN   1e-9f
#define IOU_EPS  1e-7f

// IoU exactly as reference (_iou_xyxy) with clip(.,0); fp contraction off so
// results are bit-identical across kernels and match plain IEEE numpy eval.
__device__ __forceinline__ float iou_pair(const float4 p, const float4 g) {
#pragma clang fp contract(off)
    float w1 = p.z - p.x;
    float h1 = (p.w - p.y) + IOU_EPS;
    float w2 = g.z - g.x;
    float h2 = (g.w - g.y) + IOU_EPS;
    float iw = fminf(p.z, g.z) - fmaxf(p.x, g.x);
    iw = fmaxf(iw, 0.0f);
    float ih = fminf(p.w, g.w) - fmaxf(p.y, g.y);
    ih = fmaxf(ih, 0.0f);
    float inter = iw * ih;
    float uni = w1 * h1 + w2 * h2 - inter + IOU_EPS;
    float r = inter / uni;
    return fmaxf(r, 0.0f);
}

// mask_gt dtype detection (int32 / f32 / u8), wave-uniform. mask[b][0] is
// always true (n_gt>=1) so each dtype is observable in the first nw words.
__device__ __forceinline__ int detect_mode(const void* mg, int nw) {
    const unsigned* w = (const unsigned*)mg;
    int lane = threadIdx.x & 63;
    int badI = 0, badF = 0;
    for (int i = lane; i < nw; i += 64) {
        unsigned v = w[i];
        badI |= (v > 1u);
        badF |= (v != 0u && v != 0x3F800000u);
    }
    unsigned long long bI = __ballot(badI != 0);
    unsigned long long bF = __ballot(badF != 0);
    return bI ? (bF ? 2 : 1) : 0;
}

__device__ __forceinline__ bool mask_at(const void* mg, int mode, int idx) {
    if (mode == 0) return ((const int*)mg)[idx] != 0;
    if (mode == 1) return ((const float*)mg)[idx] != 0.0f;
    return ((const unsigned char*)mg)[idx] != 0;
}

// K1: chunk task only. Per (b,ch): in-box bits -> rowbits0 (plain store),
// select1 (full-row IoU argmax for pc>1) -> tgt0, per-chunk histogram ->
// cntChunk (plain stores), pre-mask in-box OR-word -> hasinChunk.
__global__ void k_phase1(const float4* __restrict__ pdb, const float2* __restrict__ anc,
                         const float4* __restrict__ gtb, const void* mg, int nw,
                         unsigned* __restrict__ rowbits0, short* __restrict__ tgt0,
                         int* __restrict__ cntChunk, unsigned* __restrict__ hasinChunk,
                         int A, int M, int nCh) {
    int b = blockIdx.y, ch = blockIdx.x, tid = threadIdx.x;
    int lane = tid & 63, wid = tid >> 6;
    int mode = detect_mode(mg, nw);
    size_t bA = (size_t)b * A;
    __shared__ float4 sg[32];
    __shared__ unsigned char smg[32];
    __shared__ int shist[32];
    __shared__ unsigned sOr[4];
    if (tid < 32) {
        sg[tid]    = (tid < M) ? gtb[b * M + tid] : make_float4(0.f, 0.f, 0.f, 0.f);
        smg[tid]   = (tid < M) && mask_at(mg, mode, b * M + tid) ? 1 : 0;
        shist[tid] = 0;
    }
    __syncthreads();
    int a = ch * 256 + tid;
    unsigned inboxRaw = 0u, bits = 0u;
    if (a < A) {
        float2 an = anc[a];
        for (int m = 0; m < M; m++) {
            float4 g = sg[m];
            float mn = fminf(fminf(an.x - g.x, an.y - g.y), fminf(g.z - an.x, g.w - an.y));
            if (mn > EPS_IN) {
                inboxRaw |= (1u << m);
                if (smg[m]) bits |= (1u << m);
            }
        }
        rowbits0[bA + a] = bits;
        int pc = __popc(bits);
        int t;
        if (pc > 1) {
            float4 p = pdb[bA + a];
            float bv = -1.0f; int bm = 0;
            for (int m = 0; m < M; m++) {
                float v = iou_pair(p, sg[m]);
                if (v > bv) { bv = v; bm = m; }
            }
            t = bm;                       // full-row first-max (ties: lowest m)
        } else if (pc == 1) t = __ffs(bits) - 1;
        else t = -1;
        tgt0[bA + a] = (short)t;
        if (t >= 0) atomicAdd(&shist[t], 1);
    }
    // pre-mask in-box OR across the block (for fix1's need1 in k_final)
    unsigned h = inboxRaw;
    for (int off = 32; off; off >>= 1) h |= __shfl_xor(h, off);
    if (lane == 0) sOr[wid] = h;
    __syncthreads();
    if (tid < 32) cntChunk[((size_t)b * nCh + ch) * 32 + tid] = shist[tid];
    if (tid == 0) hasinChunk[b * nCh + ch] = sOr[0] | sOr[1] | sOr[2] | sOr[3];
}

// K2: prologue: (A) wave 0 sums cnt0, ORs hasin, flags columns that can
// ever need colKey (masked && (cnt0<=M || !hasin)); (B) all 256 threads
// compute the A-scan argmax for each flagged column -> LDS colKey;
// (C) wave 0 runs fix1 groups + fix2 32-step register scan, recording the
// override list; (D) finalize overrides -> final tgt per entry. Main pass:
// t = tgt0 (short load) unless overridden; 1 IoU; gather; writes; fused ts.
__global__ void k_final(const float* __restrict__ pds, const float4* __restrict__ pdb,
                        const float4* __restrict__ gtb, const int* __restrict__ gtl,
                        const void* mg, int nw,
                        const unsigned* __restrict__ rowbits0,
                        const short* __restrict__ tgt0,
                        const int* __restrict__ cntChunk,
                        const unsigned* __restrict__ hasinChunk,
                        float* __restrict__ out,
                        int A, int M, int C, int B, int nCh) {
    int b = blockIdx.y;
    int base = blockIdx.x * 256;
    int tid = threadIdx.x;
    int lane = tid & 63, wid = tid >> 6;
    int mode = detect_mode(mg, nw);
    size_t bA = (size_t)b * A;
    __shared__ float4 sg[32];
    __shared__ int slab[32];
    __shared__ int sCnt0[32];
    __shared__ unsigned long long sColKey[32];
    __shared__ unsigned sFlagBits, sHorAll;
    __shared__ unsigned long long sred[4];
    __shared__ int ovrA[64];
    __shared__ unsigned ovrAdd[64];
    __shared__ short ovrT[64];
    __shared__ int sNov;
    __shared__ float snorm[256];
    __shared__ int stl[256];
    if (tid < 32) {
        sg[tid]   = (tid < M) ? gtb[b * M + tid] : make_float4(0.f, 0.f, 0.f, 0.f);
        slab[tid] = (tid < M) ? gtl[b * M + tid] : 0;
    }
    __syncthreads();

    // ---- stage A: cnt0 / hasin / flagged set (wave 0) ----
    if (tid < 64) {
        unsigned h = 0u;
        for (int ch = tid; ch < nCh; ch += 64) h |= hasinChunk[b * nCh + ch];
        for (int off = 32; off; off >>= 1) h |= __shfl_xor(h, off);
        int c0 = 0;
        if (tid < 32) {
            for (int ch = 0; ch < nCh; ch++)
                c0 += cntChunk[((size_t)b * nCh + ch) * 32 + tid];
        }
        bool mv = (tid < M) && mask_at(mg, mode, b * M + tid);
        // colKey can only ever be consumed if cnt0 can reach 0 (<=M total
        // decrements in the <=M-step scan) or fix1 fires (!hasin => cnt0==0).
        bool flag = mv && (c0 <= M);
        unsigned fb = (unsigned)__ballot(flag);
        if (tid < 32) sCnt0[tid] = c0;
        if (tid == 0) { sFlagBits = fb; sHorAll = h; }
    }
    __syncthreads();

    // ---- stage B: A-scan argmax for flagged columns (all 256 threads) ----
    unsigned fbits = sFlagBits;
    while (fbits) {
        int m = __ffs(fbits) - 1; fbits &= fbits - 1;
        float4 gm = sg[m];
        unsigned long long key = 0ull;
        for (int aa = tid; aa < A; aa += 256) {
            float vv = iou_pair(pdb[bA + aa], gm);
            unsigned long long k2 =
                ((unsigned long long)__float_as_uint(vv) << 32) |
                (0xFFFFFFFFu - (unsigned)aa);
            if (k2 > key) key = k2;
        }
        for (int off = 32; off; off >>= 1) {
            unsigned long long o = __shfl_down(key, off);
            if (o > key) key = o;
        }
        if (lane == 0) sred[wid] = key;
        __syncthreads();
        if (tid == 0) {
            unsigned long long k3 = sred[0];
            for (int i = 1; i < 4; i++) if (sred[i] > k3) k3 = sred[i];
            sColKey[m] = k3;
        }
        __syncthreads();
    }

    // ---- stage C: fix1 + fix2 serial tail (wave 0, registers) ----
    if (tid < 64) {
        unsigned flagBits = sFlagBits, horAll = sHorAll;
        bool mv   = (tid < M) && mask_at(mg, mode, b * M + tid);
        bool flag = (tid < 32) && ((flagBits >> tid) & 1u);
        int best = -1;
        if (flag) {
            unsigned long long key = sColKey[tid];
            best = (int)(0xFFFFFFFFu - (unsigned)(key & 0xFFFFFFFFull));
        }
        bool needv = mv && !((horAll >> tid) & 1u);        // fix1 need
        int c0 = (tid < 32) ? sCnt0[tid] : 0;
        int myPre = (best >= 0) ? (int)tgt0[bA + best] : -1;
        unsigned maskbits = (unsigned)__ballot(mv);
        unsigned needBits = (unsigned)__ballot(needv);
        unsigned myEq = 0u;
        for (int g2 = 0; g2 < 32; g2++) {
            int bb = __shfl(best, g2);
            if (bb == best) myEq |= (1u << g2);
        }
        int nov = 0;
        // fix1: groups of needy gts sharing the same best anchor
        unsigned rem = needBits;
        while (rem) {
            int gl = __ffs(rem) - 1;
            unsigned em = __shfl(myEq, gl) & needBits;
            rem &= ~em;
            int aF = __shfl(best, gl);
            unsigned addb = em;
            unsigned bits1 = rowbits0[bA + aF] | addb;
            int t1;
            if (__popc(bits1) > 1) {
                float4 p = pdb[bA + aF];
                unsigned long long kk = 0ull;
                if (tid < M) {
                    float vv = iou_pair(p, sg[tid]);
                    kk = ((unsigned long long)__float_as_uint(vv) << 32) |
                         (0xFFFFFFFFu - (unsigned)tid);
                }
                for (int off = 32; off; off >>= 1) {
                    unsigned long long o = __shfl_down(kk, off);
                    if (o > kk) kk = o;
                }
                kk = __shfl(kk, 0);
                t1 = (int)(0xFFFFFFFFu - (unsigned)(kk & 0xFFFFFFFFull));
            } else {
                t1 = __ffs(bits1) - 1;
            }
            int t0a = __shfl(myPre, gl);
            if (tid == t0a && t0a >= 0) c0--;
            if (tid == t1) c0++;
            if (best == aF) myPre = t1;
            if (tid == 0) { ovrA[nov] = aF; ovrAdd[nov] = addb; }
            nov++;
        }
        // fix2: order-dependent 32-step scan in registers
        unsigned applied = 0u;
        for (int g = 0; g < M; g++) {
            int cg = __shfl(c0, g);
            if (((maskbits >> g) & 1u) && cg == 0) {
                int aa      = __shfl(best, g);
                unsigned em = __shfl(myEq, g);
                unsigned x  = applied & em;
                int old;
                if (x) old = 31 - __clz(x);    // last earlier step took this anchor
                else   old = __shfl(myPre, g); // owner after fix1 (-1 = background)
                if (tid == old) c0--;
                if (tid == g)   c0++;
                applied |= (1u << g);
                if (tid == 0) { ovrA[nov] = aa; ovrAdd[nov] = 1u << g; }
                nov++;
            }
        }
        if (tid == 0) sNov = nov;
    }
    __syncthreads();
    // ---- stage D: finalize overrides -> final tgt (wave 0) ----
    if (tid < 64) {
        int nov2 = sNov;
        for (int j = 0; j < nov2; j++) {
            int aj = ovrA[j];
            unsigned addT = 0u;
            for (int k = 0; k < nov2; k++) if (ovrA[k] == aj) addT |= ovrAdd[k];
            unsigned bt = rowbits0[bA + aj] | addT;
            int tf;
            if (__popc(bt) > 1) {
                float4 p = pdb[bA + aj];
                unsigned long long kk = 0ull;
                if (tid < M) {
                    float vv = iou_pair(p, sg[tid]);
                    kk = ((unsigned long long)__float_as_uint(vv) << 32) |
                         (0xFFFFFFFFu - (unsigned)tid);
                }
                for (int off = 32; off; off >>= 1) {
                    unsigned long long o = __shfl_down(kk, off);
                    if (o > kk) kk = o;
                }
                kk = __shfl(kk, 0);
                tf = (int)(0xFFFFFFFFu - (unsigned)(kk & 0xFFFFFFFFull));
            } else {
                tf = __ffs(bt) - 1;
            }
            if (tid == 0) ovrT[j] = (short)tf;
        }
    }
    __syncthreads();

    // ---- main: per-anchor outputs (no argmax; tgt0 + override list) ----
    int a = base + tid;
    size_t BA = (size_t)B * A;
    if (a < A) {
        size_t idx = bA + a;
        int t = (int)tgt0[idx];
        int nov2 = sNov;
        for (int j = 0; j < nov2; j++)
            if (ovrA[j] == a) t = (int)ovrT[j];
        int fg = (t >= 0);
        int tgtO = fg ? t : 0;
        int lab = slab[tgtO];
        int tl = min(max(lab, 0), C);            // clip(., 0, NUM_CLASSES)
        float norm = 0.0f;
        if (fg) {
            float ov = iou_pair(pdb[idx], sg[t]);
            int li = (lab >= 0 && lab < C) ? lab : 0;
            float cls = pds[idx * (size_t)C + li];
            float ov6 = powf(ov, 6.0f);          // overlaps ** BETA
            float vv = cls * ov6;                // align_metric at (a, tgt)
            norm = vv * ov / (vv + 1e-9f);       // pam*pov/(pam+eps)
        }
        out[idx] = (float)tl;                                // tl
        ((float4*)(out + BA))[idx] = sg[tgtO];               // tb
        out[BA * (size_t)(5 + C) + idx] = fg ? 1.0f : 0.0f;  // fg
        out[BA * (size_t)(6 + C) + idx] = (float)tgtO;       // tgt
        snorm[tid] = norm;
        stl[tid] = tl;
    }
    __syncthreads();
    int cntA = min(256, A - base);
    int rowf4 = C >> 2;
    int nf4 = cntA * rowf4;
    float4* tsb = (float4*)(out + BA * 5 + (bA + base) * C);
    int q = 256 / rowf4, r = 256 - q * rowf4;
    int row = tid / rowf4;
    int c4  = tid - row * rowf4;
    for (int i = tid; i < nf4; i += 256) {
        float nv = snorm[row];
        int tl   = stl[row];
        int cb = c4 * 4;
        float4 vv;
        vv.x = (tl == cb + 0) ? nv : 0.0f;
        vv.y = (tl == cb + 1) ? nv : 0.0f;
        vv.z = (tl == cb + 2) ? nv : 0.0f;
        vv.w = (tl == cb + 3) ? nv : 0.0f;
        tsb[i] = vv;
        row += q; c4 += r;
        if (c4 >= rowf4) { c4 -= rowf4; row++; }
    }
}

extern "C" void kernel_launch(void* const* d_in, const int* in_sizes, int n_in,
                              void* d_out, int out_size, void* d_ws, size_t ws_size,
                              hipStream_t stream) {
    const float*  pd_scores = (const float*)d_in[0];
    const float4* pd_bboxes = (const float4*)d_in[1];
    const float2* anc       = (const float2*)d_in[2];
    const int*    gt_labels = (const int*)d_in[3];
    const float4* gt_bboxes = (const float4*)d_in[4];
    const void*   mask_gt   = d_in[5];

    int A = in_sizes[2] / 2;
    int B = in_sizes[1] / (A * 4);
    int M = in_sizes[3] / B;
    int C = (int)((long long)in_sizes[0] / ((long long)B * A));
    int nCh = (A + 255) / 256;
    int nw = (B * M) / 4; if (nw > 256) nw = 256;

    char* wp = (char*)d_ws;
    auto carve = [&](size_t bytes) -> char* {
        char* r = wp; wp += (bytes + 255) & ~(size_t)255; return r;
    };
    unsigned* rowbits0   = (unsigned*)carve((size_t)B * A * 4);
    short* tgt0          = (short*)carve((size_t)B * A * 2);
    int* cntChunk        = (int*)carve((size_t)B * nCh * 32 * 4);
    unsigned* hasinChunk = (unsigned*)carve((size_t)B * nCh * 4);

    float* out = (float*)d_out;

    k_phase1<<<dim3(nCh, B), 256, 0, stream>>>(pd_bboxes, anc, gt_bboxes, mask_gt, nw,
                                               rowbits0, tgt0, cntChunk, hasinChunk,
                                               A, M, nCh);
    k_final<<<dim3(nCh, B), 256, 0, stream>>>(pd_scores, pd_bboxes, gt_bboxes, gt_labels,
                                              mask_gt, nw, rowbits0, tgt0, cntChunk,
                                              hasinChunk, out, A, M, C, B, nCh);
}

// Round 14
// 65.693 us; speedup vs baseline: 1.4359x; 1.4359x over previous
//
#include <hip/hip_runtime.h>

// ---------------------------------------------------------------------------
// TaskAlignedAssigner (YOLO TAL) for MI355X — 2 dispatches.
// B=32, A=8400, M=32, C=80 (derived at runtime; M<=32 so a gt-column mask
// fits one uint32 per anchor; C%4==0 assumed for float4 ts writes).
//
// Outputs (concatenated float32, return order):
//   tl (B,A) | tb (B,A,4) | ts (B,A,C) | fg (B,A) | tgt (B,A)
//
// R1:  removed global atomic histogram (65us same-cacheline serialization).
// R2:  fix2 wave-parallel register scan (was 71.7us dependent-latency).
// R3  (regressed): select1 inside 32-block fix2 -> 32/256 CUs busy.
// R4:  select1 full-grid; 5 kernels + memset = 74.5us.
// R5  (regressed, 250us): cooperative kernel — grid.sync ~60-70us each.
// R6  (regressed, 127us): ticket+__threadfence — ~90us of L2 writeback.
// R7:  4 dispatches, no fences: 59.9us.
// R8:  2 dispatches (columns+chunks merged; override-list k_final): 53.3us.
// R9  (regressed, 91us): per-chunk column reduce -> v[32] scratch spill.
// R10: R8 phase1 + light main pass (tgt=tgt0 unless overridden): 51.7us.
// R11 (regressed, 94us): flagged-column A-scan in k_final prologue — the
//      prologue is replicated 33x per batch; only O(1) tails may be
//      replicated. Reverted.
// R12: R10 + (a) quad-column tasks: 4 columns/block with NAMED key regs
//      (pdb L2 traffic 137MB -> 34MB, blocks 1024 -> 256); (b) nontemporal
//      stores for all k_final output streams (92MB write-once).
// R13: compile fix — __builtin_nontemporal_store needs a native clang
//      vector type, not HIP_vector_type float4; added nf4 ext_vector alias.
// ---------------------------------------------------------------------------

#define EPS_IN   1e-9f
#define IOU_EPS  1e-7f

typedef float nf4 __attribute__((ext_vector_type(4)));

__device__ __forceinline__ void nt_store4(float4 v, float4* p) {
    nf4 t; t.x = v.x; t.y = v.y; t.z = v.z; t.w = v.w;
    __builtin_nontemporal_store(t, (nf4*)p);
}

// IoU exactly as reference (_iou_xyxy) with clip(.,0); fp contraction off so
// results are bit-identical across kernels and match plain IEEE numpy eval.
__device__ __forceinline__ float iou_pair(const float4 p, const float4 g) {
#pragma clang fp contract(off)
    float w1 = p.z - p.x;
    float h1 = (p.w - p.y) + IOU_EPS;
    float w2 = g.z - g.x;
    float h2 = (g.w - g.y) + IOU_EPS;
    float iw = fminf(p.z, g.z) - fmaxf(p.x, g.x);
    iw = fmaxf(iw, 0.0f);
    float ih = fminf(p.w, g.w) - fmaxf(p.y, g.y);
    ih = fmaxf(ih, 0.0f);
    float inter = iw * ih;
    float uni = w1 * h1 + w2 * h2 - inter + IOU_EPS;
    float r = inter / uni;
    return fmaxf(r, 0.0f);
}

// mask_gt dtype detection (int32 / f32 / u8), wave-uniform. mask[b][0] is
// always true (n_gt>=1) so each dtype is observable in the first nw words.
__device__ __forceinline__ int detect_mode(const void* mg, int nw) {
    const unsigned* w = (const unsigned*)mg;
    int lane = threadIdx.x & 63;
    int badI = 0, badF = 0;
    for (int i = lane; i < nw; i += 64) {
        unsigned v = w[i];
        badI |= (v > 1u);
        badF |= (v != 0u && v != 0x3F800000u);
    }
    unsigned long long bI = __ballot(badI != 0);
    unsigned long long bF = __ballot(badF != 0);
    return bI ? (bF ? 2 : 1) : 0;
}

__device__ __forceinline__ bool mask_at(const void* mg, int mode, int idx) {
    if (mode == 0) return ((const int*)mg)[idx] != 0;
    if (mode == 1) return ((const float*)mg)[idx] != 0.0f;
    return ((const unsigned char*)mg)[idx] != 0;
}

// K1: merged quad-column + chunk pass (independent halves, disjoint outputs).
//  blockIdx.x <  nColBlk : quad-column task (b, m0=4*x..+3): per masked col
//                          colKey (argmax_a overlaps, first-index tiebreak)
//                          + hasin -> needByte. 4 named key regs, one pdb
//                          load serves 4 IoUs.
//  blockIdx.x >= nColBlk : chunk task (b,ch): in-box bits -> rowbits0,
//                          select1 -> tgt0, per-chunk histogram -> cntChunk.
__global__ void k_phase1(const float4* __restrict__ pdb, const float2* __restrict__ anc,
                         const float4* __restrict__ gtb, const void* mg, int nw,
                         unsigned long long* __restrict__ colKey,
                         unsigned char* __restrict__ needByte,
                         unsigned* __restrict__ rowbits0, short* __restrict__ tgt0,
                         int* __restrict__ cntChunk,
                         int A, int M, int nCh, int nColBlk) {
    int b = blockIdx.y, tid = threadIdx.x;
    int mode = detect_mode(mg, nw);
    size_t bA = (size_t)b * A;

    if ((int)blockIdx.x < nColBlk) {
        // ---- quad-column task ----
        int m0 = blockIdx.x * 4;
        bool mv0 = (m0 + 0 < M) && mask_at(mg, mode, b * M + m0 + 0);
        bool mv1 = (m0 + 1 < M) && mask_at(mg, mode, b * M + m0 + 1);
        bool mv2 = (m0 + 2 < M) && mask_at(mg, mode, b * M + m0 + 2);
        bool mv3 = (m0 + 3 < M) && mask_at(mg, mode, b * M + m0 + 3);
        if (!(mv0 || mv1 || mv2 || mv3)) return;
        float4 z = make_float4(0.f, 0.f, 0.f, 0.f);
        float4 g0 = mv0 ? gtb[b * M + m0 + 0] : z;
        float4 g1 = mv1 ? gtb[b * M + m0 + 1] : z;
        float4 g2 = mv2 ? gtb[b * M + m0 + 2] : z;
        float4 g3 = mv3 ? gtb[b * M + m0 + 3] : z;
        unsigned long long k0 = 0, k1 = 0, k2 = 0, k3 = 0;
        int h0 = 0, h1 = 0, h2 = 0, h3 = 0;
        for (int a = tid; a < A; a += 256) {
            float4 p = pdb[bA + a];
            float2 an = anc[a];
            unsigned inv = 0xFFFFFFFFu - (unsigned)a;
            {
                float v = iou_pair(p, g0);
                unsigned long long k = ((unsigned long long)__float_as_uint(v) << 32) | inv;
                if (k > k0) k0 = k;
                float mn = fminf(fminf(an.x - g0.x, an.y - g0.y), fminf(g0.z - an.x, g0.w - an.y));
                h0 |= (mn > EPS_IN);
            }
            {
                float v = iou_pair(p, g1);
                unsigned long long k = ((unsigned long long)__float_as_uint(v) << 32) | inv;
                if (k > k1) k1 = k;
                float mn = fminf(fminf(an.x - g1.x, an.y - g1.y), fminf(g1.z - an.x, g1.w - an.y));
                h1 |= (mn > EPS_IN);
            }
            {
                float v = iou_pair(p, g2);
                unsigned long long k = ((unsigned long long)__float_as_uint(v) << 32) | inv;
                if (k > k2) k2 = k;
                float mn = fminf(fminf(an.x - g2.x, an.y - g2.y), fminf(g2.z - an.x, g2.w - an.y));
                h2 |= (mn > EPS_IN);
            }
            {
                float v = iou_pair(p, g3);
                unsigned long long k = ((unsigned long long)__float_as_uint(v) << 32) | inv;
                if (k > k3) k3 = k;
                float mn = fminf(fminf(an.x - g3.x, an.y - g3.y), fminf(g3.z - an.x, g3.w - an.y));
                h3 |= (mn > EPS_IN);
            }
        }
        int lane = tid & 63, wid = tid >> 6;
        for (int off = 32; off; off >>= 1) {
            unsigned long long o;
            o = __shfl_down(k0, off); if (o > k0) k0 = o;
            o = __shfl_down(k1, off); if (o > k1) k1 = o;
            o = __shfl_down(k2, off); if (o > k2) k2 = o;
            o = __shfl_down(k3, off); if (o > k3) k3 = o;
            h0 |= __shfl_down(h0, off);
            h1 |= __shfl_down(h1, off);
            h2 |= __shfl_down(h2, off);
            h3 |= __shfl_down(h3, off);
        }
        __shared__ unsigned long long sk[4][4];
        __shared__ int sh[4][4];
        if (lane == 0) {
            sk[wid][0] = k0; sk[wid][1] = k1; sk[wid][2] = k2; sk[wid][3] = k3;
            sh[wid][0] = h0; sh[wid][1] = h1; sh[wid][2] = h2; sh[wid][3] = h3;
        }
        __syncthreads();
        if (tid < 4) {
            int j = tid, m = m0 + j;
            bool mvj = (m < M) && mask_at(mg, mode, b * M + m);
            if (mvj) {
                unsigned long long key = sk[0][j];
                int hh = sh[0][j];
                for (int w = 1; w < 4; w++) {
                    if (sk[w][j] > key) key = sk[w][j];
                    hh |= sh[w][j];
                }
                colKey[b * M + m] = key;
                needByte[b * M + m] = hh ? 0 : 1;
            }
        }
    } else {
        // ---- chunk task ----
        int ch = blockIdx.x - nColBlk;
        int a = ch * 256 + tid;
        __shared__ float4 sg[32];
        __shared__ unsigned char smg[32];
        __shared__ int shist[32];
        if (tid < 32) {
            sg[tid]    = (tid < M) ? gtb[b * M + tid] : make_float4(0.f, 0.f, 0.f, 0.f);
            smg[tid]   = (tid < M) && mask_at(mg, mode, b * M + tid) ? 1 : 0;
            shist[tid] = 0;
        }
        __syncthreads();
        if (a < A) {
            float2 an = anc[a];
            unsigned bits = 0u;
            for (int m = 0; m < M; m++) {
                float4 g = sg[m];
                float mn = fminf(fminf(an.x - g.x, an.y - g.y), fminf(g.z - an.x, g.w - an.y));
                if (mn > EPS_IN && smg[m]) bits |= (1u << m);
            }
            rowbits0[bA + a] = bits;
            int pc = __popc(bits);
            int t;
            if (pc > 1) {
                float4 p = pdb[bA + a];
                float bv = -1.0f; int bm = 0;
                for (int m = 0; m < M; m++) {
                    float v = iou_pair(p, sg[m]);
                    if (v > bv) { bv = v; bm = m; }
                }
                t = bm;                       // full-row first-max (ties: lowest m)
            } else if (pc == 1) t = __ffs(bits) - 1;
            else t = -1;
            tgt0[bA + a] = (short)t;
            if (t >= 0) atomicAdd(&shist[t], 1);
        }
        __syncthreads();
        if (tid < 32) cntChunk[((size_t)b * nCh + ch) * 32 + tid] = shist[tid];
    }
}

// K2: prologue (wave 0, O(1) work only): cnt0 = sum cntChunk; fix1 groups
// (adjust counts + pre-owners, record adds); fix2 32-step register scan
// (record adds); finalize override list -> final tgt per overridden anchor.
// Main pass: t = tgt0 (short load) unless overridden; 1 IoU; gather;
// nontemporal writes; block-cooperative float4 ts write.
__global__ void k_final(const float* __restrict__ pds, const float4* __restrict__ pdb,
                        const float4* __restrict__ gtb, const int* __restrict__ gtl,
                        const void* mg, int nw,
                        const unsigned long long* __restrict__ colKey,
                        const unsigned char* __restrict__ needByte,
                        const unsigned* __restrict__ rowbits0,
                        const short* __restrict__ tgt0,
                        const int* __restrict__ cntChunk,
                        float* __restrict__ out,
                        int A, int M, int C, int B, int nCh) {
    int b = blockIdx.y;
    int base = blockIdx.x * 256;
    int tid = threadIdx.x;
    int mode = detect_mode(mg, nw);
    size_t bA = (size_t)b * A;
    __shared__ float4 sg[32];
    __shared__ int slab[32];
    __shared__ int ovrA[64];
    __shared__ unsigned ovrAdd[64];
    __shared__ short ovrT[64];
    __shared__ int sNov;
    __shared__ float snorm[256];
    __shared__ int stl[256];
    if (tid < 32) {
        sg[tid]   = (tid < M) ? gtb[b * M + tid] : make_float4(0.f, 0.f, 0.f, 0.f);
        slab[tid] = (tid < M) ? gtl[b * M + tid] : 0;
    }
    __syncthreads();

    if (tid < 64) {
        // ---- lane state (lane g<32 owns gt g) ----
        bool mv = false, needv = false;
        int best = -1, c0 = 0;
        if (tid < M) mv = mask_at(mg, mode, b * M + tid);
        if (mv) {
            unsigned long long key = colKey[b * M + tid];
            best = (int)(0xFFFFFFFFu - (unsigned)(key & 0xFFFFFFFFull));
            needv = (needByte[b * M + tid] != 0);
        }
        if (tid < 32) {
            for (int ch = 0; ch < nCh; ch++)
                c0 += cntChunk[((size_t)b * nCh + ch) * 32 + tid];
        }
        int myPre = (mv && best >= 0) ? (int)tgt0[bA + best] : -1;
        unsigned maskbits = (unsigned)__ballot(mv);
        unsigned needBits = (unsigned)__ballot(needv);
        unsigned myEq = 0u;
        for (int g2 = 0; g2 < 32; g2++) {
            int bb = __shfl(best, g2);
            if (bb == best) myEq |= (1u << g2);
        }
        int nov = 0;
        // ---- fix1: groups of needy gts sharing the same best anchor ----
        unsigned rem = needBits;
        while (rem) {
            int gl = __ffs(rem) - 1;                       // group leader
            unsigned em = __shfl(myEq, gl) & needBits;     // group members
            rem &= ~em;
            int aF = __shfl(best, gl);
            unsigned addb = em;                            // bits added to aF
            unsigned bits1 = rowbits0[bA + aF] | addb;
            int t1;
            if (__popc(bits1) > 1) {
                // select1 recompute: full-row IoU argmax (first-max tiebreak)
                float4 p = pdb[bA + aF];
                unsigned long long kk = 0ull;
                if (tid < M) {
                    float vv = iou_pair(p, sg[tid]);
                    kk = ((unsigned long long)__float_as_uint(vv) << 32) |
                         (0xFFFFFFFFu - (unsigned)tid);
                }
                for (int off = 32; off; off >>= 1) {
                    unsigned long long o = __shfl_down(kk, off);
                    if (o > kk) kk = o;
                }
                kk = __shfl(kk, 0);
                t1 = (int)(0xFFFFFFFFu - (unsigned)(kk & 0xFFFFFFFFull));
            } else {
                t1 = __ffs(bits1) - 1;                     // bits0 was empty
            }
            int t0a = __shfl(myPre, gl);                   // tgt0[aF]
            if (tid == t0a && t0a >= 0) c0--;              // count adjust
            if (tid == t1) c0++;
            if (best == aF) myPre = t1;                    // new pre-owner
            if (tid == 0) { ovrA[nov] = aF; ovrAdd[nov] = addb; }
            nov++;
        }
        // ---- fix2: order-dependent 32-step scan in registers ----
        unsigned applied = 0u;
        for (int g = 0; g < M; g++) {
            int cg = __shfl(c0, g);
            if (((maskbits >> g) & 1u) && cg == 0) {
                int aa      = __shfl(best, g);
                unsigned em = __shfl(myEq, g);
                unsigned x  = applied & em;
                int old;
                if (x) old = 31 - __clz(x);    // last earlier step took this anchor
                else   old = __shfl(myPre, g); // owner after fix1 (-1 = background)
                if (tid == old) c0--;
                if (tid == g)   c0++;
                applied |= (1u << g);
                if (tid == 0) { ovrA[nov] = aa; ovrAdd[nov] = 1u << g; }
                nov++;
            }
        }
        if (tid == 0) sNov = nov;
    }
    __syncthreads();
    // ---- finalize overrides: final tgt per entry (wave 0) ----
    if (tid < 64) {
        int nov2 = sNov;
        for (int j = 0; j < nov2; j++) {
            int aj = ovrA[j];
            unsigned addT = 0u;
            for (int k = 0; k < nov2; k++) if (ovrA[k] == aj) addT |= ovrAdd[k];
            unsigned bt = rowbits0[bA + aj] | addT;
            int tf;
            if (__popc(bt) > 1) {
                float4 p = pdb[bA + aj];
                unsigned long long kk = 0ull;
                if (tid < M) {
                    float vv = iou_pair(p, sg[tid]);
                    kk = ((unsigned long long)__float_as_uint(vv) << 32) |
                         (0xFFFFFFFFu - (unsigned)tid);
                }
                for (int off = 32; off; off >>= 1) {
                    unsigned long long o = __shfl_down(kk, off);
                    if (o > kk) kk = o;
                }
                kk = __shfl(kk, 0);
                tf = (int)(0xFFFFFFFFu - (unsigned)(kk & 0xFFFFFFFFull));
            } else {
                tf = __ffs(bt) - 1;
            }
            if (tid == 0) ovrT[j] = (short)tf;
        }
    }
    __syncthreads();

    // ---- main: per-anchor outputs (no argmax; tgt0 + override list) ----
    int a = base + tid;
    size_t BA = (size_t)B * A;
    if (a < A) {
        size_t idx = bA + a;
        int t = (int)tgt0[idx];
        int nov2 = sNov;
        for (int j = 0; j < nov2; j++)
            if (ovrA[j] == a) t = (int)ovrT[j];
        int fg = (t >= 0);
        int tgtO = fg ? t : 0;
        int lab = slab[tgtO];
        int tl = min(max(lab, 0), C);            // clip(., 0, NUM_CLASSES)
        float norm = 0.0f;
        if (fg) {
            float ov = iou_pair(pdb[idx], sg[t]);
            int li = (lab >= 0 && lab < C) ? lab : 0;
            float cls = pds[idx * (size_t)C + li];
            float ov6 = powf(ov, 6.0f);          // overlaps ** BETA
            float vv = cls * ov6;                // align_metric at (a, tgt)
            norm = vv * ov / (vv + 1e-9f);       // pam*pov/(pam+eps)
        }
        __builtin_nontemporal_store((float)tl, &out[idx]);                       // tl
        nt_store4(sg[tgtO], &((float4*)(out + BA))[idx]);                        // tb
        __builtin_nontemporal_store(fg ? 1.0f : 0.0f,
                                    &out[BA * (size_t)(5 + C) + idx]);           // fg
        __builtin_nontemporal_store((float)tgtO,
                                    &out[BA * (size_t)(6 + C) + idx]);           // tgt
        snorm[tid] = norm;
        stl[tid] = tl;
    }
    __syncthreads();
    int cntA = min(256, A - base);
    int rowf4 = C >> 2;
    int nf4 = cntA * rowf4;
    float4* tsb = (float4*)(out + BA * 5 + (bA + base) * C);
    int q = 256 / rowf4, r = 256 - q * rowf4;
    int row = tid / rowf4;
    int c4  = tid - row * rowf4;
    for (int i = tid; i < nf4; i += 256) {
        float nv = snorm[row];
        int tl   = stl[row];
        int cb = c4 * 4;
        float4 vv;
        vv.x = (tl == cb + 0) ? nv : 0.0f;
        vv.y = (tl == cb + 1) ? nv : 0.0f;
        vv.z = (tl == cb + 2) ? nv : 0.0f;
        vv.w = (tl == cb + 3) ? nv : 0.0f;
        nt_store4(vv, &tsb[i]);
        row += q; c4 += r;
        if (c4 >= rowf4) { c4 -= rowf4; row++; }
    }
}

extern "C" void kernel_launch(void* const* d_in, const int* in_sizes, int n_in,
                              void* d_out, int out_size, void* d_ws, size_t ws_size,
                              hipStream_t stream) {
    const float*  pd_scores = (const float*)d_in[0];
    const float4* pd_bboxes = (const float4*)d_in[1];
    const float2* anc       = (const float2*)d_in[2];
    const int*    gt_labels = (const int*)d_in[3];
    const float4* gt_bboxes = (const float4*)d_in[4];
    const void*   mask_gt   = d_in[5];

    int A = in_sizes[2] / 2;
    int B = in_sizes[1] / (A * 4);
    int M = in_sizes[3] / B;
    int C = (int)((long long)in_sizes[0] / ((long long)B * A));
    int nCh = (A + 255) / 256;
    int nColBlk = (M + 3) / 4;
    int nw = (B * M) / 4; if (nw > 256) nw = 256;

    char* wp = (char*)d_ws;
    auto carve = [&](size_t bytes) -> char* {
        char* r = wp; wp += (bytes + 255) & ~(size_t)255; return r;
    };
    unsigned* rowbits0         = (unsigned*)carve((size_t)B * A * 4);
    short* tgt0                = (short*)carve((size_t)B * A * 2);
    unsigned long long* colKey = (unsigned long long*)carve((size_t)B * M * 8);
    unsigned char* needByte    = (unsigned char*)carve((size_t)B * M);
    int* cntChunk              = (int*)carve((size_t)B * nCh * 32 * 4);

    float* out = (float*)d_out;

    k_phase1<<<dim3(nColBlk + nCh, B), 256, 0, stream>>>(
        pd_bboxes, anc, gt_bboxes, mask_gt, nw, colKey, needByte,
        rowbits0, tgt0, cntChunk, A, M, nCh, nColBlk);
    k_final<<<dim3(nCh, B), 256, 0, stream>>>(pd_scores, pd_bboxes, gt_bboxes, gt_labels,
                                              mask_gt, nw, colKey, needByte, rowbits0,
                                              tgt0, cntChunk, out, A, M, C, B, nCh);
}

// Round 15
// 51.901 us; speedup vs baseline: 1.8175x; 1.2657x over previous
//
#include <hip/hip_runtime.h>

// ---------------------------------------------------------------------------
// TaskAlignedAssigner (YOLO TAL) for MI355X — 2 dispatches. (R10 revert)
// B=32, A=8400, M=32, C=80 (derived at runtime; M<=32 so a gt-column mask
// fits one uint32 per anchor; C%4==0 assumed for float4 ts writes).
//
// Outputs (concatenated float32, return order):
//   tl (B,A) | tb (B,A,4) | ts (B,A,C) | fg (B,A) | tgt (B,A)
//
// R1:  removed global atomic histogram (65us same-cacheline serialization).
// R2:  fix2 wave-parallel register scan (was 71.7us dependent-latency).
// R3  (regressed): select1 inside 32-block fix2 -> 32/256 CUs busy.
// R4:  select1 full-grid; 5 kernels + memset = 74.5us.
// R5  (regressed, 250us): cooperative kernel — grid.sync ~60-70us each.
// R6  (regressed, 127us): ticket+__threadfence — ~90us of L2 writeback.
// R7:  4 dispatches, no fences: 59.9us.
// R8:  2 dispatches (columns+chunks merged; override-list k_final): 53.3us.
// R9  (regressed, 91us): per-chunk column reduce -> v[32] scratch spill.
// R10: R8 phase1 + light main pass (tgt=tgt0 unless overridden): 51.7us. BEST
// R11 (regressed, 94us): flagged-column A-scan in replicated prologue.
// R12/R13/R14 (regressed, 65.7us): quad-columns (1 block/CU latency tail) +
//      nt stores (bypass L2 write-combining). Both reverted.
// R15: exact R10 revert — measured floor: write-bound k_final (92.4MB out)
//      + ~9us phase1 + 2 dispatch boundaries.
// ---------------------------------------------------------------------------

#define EPS_IN   1e-9f
#define IOU_EPS  1e-7f

// IoU exactly as reference (_iou_xyxy) with clip(.,0); fp contraction off so
// results are bit-identical across kernels and match plain IEEE numpy eval.
__device__ __forceinline__ float iou_pair(const float4 p, const float4 g) {
#pragma clang fp contract(off)
    float w1 = p.z - p.x;
    float h1 = (p.w - p.y) + IOU_EPS;
    float w2 = g.z - g.x;
    float h2 = (g.w - g.y) + IOU_EPS;
    float iw = fminf(p.z, g.z) - fmaxf(p.x, g.x);
    iw = fmaxf(iw, 0.0f);
    float ih = fminf(p.w, g.w) - fmaxf(p.y, g.y);
    ih = fmaxf(ih, 0.0f);
    float inter = iw * ih;
    float uni = w1 * h1 + w2 * h2 - inter + IOU_EPS;
    float r = inter / uni;
    return fmaxf(r, 0.0f);
}

// mask_gt dtype detection (int32 / f32 / u8), wave-uniform. mask[b][0] is
// always true (n_gt>=1) so each dtype is observable in the first nw words.
__device__ __forceinline__ int detect_mode(const void* mg, int nw) {
    const unsigned* w = (const unsigned*)mg;
    int lane = threadIdx.x & 63;
    int badI = 0, badF = 0;
    for (int i = lane; i < nw; i += 64) {
        unsigned v = w[i];
        badI |= (v > 1u);
        badF |= (v != 0u && v != 0x3F800000u);
    }
    unsigned long long bI = __ballot(badI != 0);
    unsigned long long bF = __ballot(badF != 0);
    return bI ? (bF ? 2 : 1) : 0;
}

__device__ __forceinline__ bool mask_at(const void* mg, int mode, int idx) {
    if (mode == 0) return ((const int*)mg)[idx] != 0;
    if (mode == 1) return ((const float*)mg)[idx] != 0.0f;
    return ((const unsigned char*)mg)[idx] != 0;
}

// K1: merged column+anchor pass (independent halves, disjoint outputs).
//  blockIdx.x <  M  : column task (b,m): masked -> colKey (argmax_a overlaps,
//                     first-index tiebreak) + hasin -> needByte.
//  blockIdx.x >= M  : chunk task (b,ch): in-box bits -> rowbits0 (plain),
//                     select1 (no fix1) -> tgt0, per-chunk histogram ->
//                     cntChunk[b][ch][32] (plain stores, no atomics).
__global__ void k_phase1(const float4* __restrict__ pdb, const float2* __restrict__ anc,
                         const float4* __restrict__ gtb, const void* mg, int nw,
                         unsigned long long* __restrict__ colKey,
                         unsigned char* __restrict__ needByte,
                         unsigned* __restrict__ rowbits0, short* __restrict__ tgt0,
                         int* __restrict__ cntChunk,
                         int A, int M, int nCh) {
    int b = blockIdx.y, tid = threadIdx.x;
    int mode = detect_mode(mg, nw);
    size_t bA = (size_t)b * A;

    if ((int)blockIdx.x < M) {
        // ---- column task ----
        int m = blockIdx.x;
        if (!mask_at(mg, mode, b * M + m)) return;
        float4 g = gtb[b * M + m];
        unsigned long long key = 0ull;
        int hasin = 0;
        for (int a = tid; a < A; a += 256) {
            float v = iou_pair(pdb[bA + a], g);
            unsigned long long k =
                ((unsigned long long)__float_as_uint(v) << 32) | (0xFFFFFFFFu - (unsigned)a);
            if (k > key) key = k;
            float2 an = anc[a];
            float mn = fminf(fminf(an.x - g.x, an.y - g.y), fminf(g.z - an.x, g.w - an.y));
            hasin |= (mn > EPS_IN);
        }
        __shared__ unsigned long long skey[4];
        __shared__ int sin_[4];
        int lane = tid & 63, wid = tid >> 6;
        for (int off = 32; off; off >>= 1) {
            unsigned long long o = __shfl_down(key, off);
            if (o > key) key = o;
            hasin |= __shfl_down(hasin, off);
        }
        if (lane == 0) { skey[wid] = key; sin_[wid] = hasin; }
        __syncthreads();
        if (tid == 0) {
            for (int i = 1; i < 4; i++) { if (skey[i] > key) key = skey[i]; hasin |= sin_[i]; }
            colKey[b * M + m] = key;
            needByte[b * M + m] = hasin ? 0 : 1;
        }
    } else {
        // ---- chunk task ----
        int ch = blockIdx.x - M;
        int a = ch * 256 + tid;
        __shared__ float4 sg[32];
        __shared__ unsigned char smg[32];
        __shared__ int shist[32];
        if (tid < M) {
            sg[tid]  = gtb[b * M + tid];
            smg[tid] = mask_at(mg, mode, b * M + tid) ? 1 : 0;
        }
        if (tid < 32) shist[tid] = 0;
        __syncthreads();
        if (a < A) {
            float2 an = anc[a];
            unsigned bits = 0u;
            for (int m = 0; m < M; m++) {
                float4 g = sg[m];
                float mn = fminf(fminf(an.x - g.x, an.y - g.y), fminf(g.z - an.x, g.w - an.y));
                if (mn > EPS_IN && smg[m]) bits |= (1u << m);
            }
            rowbits0[bA + a] = bits;
            int pc = __popc(bits);
            int t;
            if (pc > 1) {
                float4 p = pdb[bA + a];
                float bv = -1.0f; int bm = 0;
                for (int m = 0; m < M; m++) {
                    float v = iou_pair(p, sg[m]);
                    if (v > bv) { bv = v; bm = m; }
                }
                t = bm;
            } else if (pc == 1) t = __ffs(bits) - 1;
            else t = -1;
            tgt0[bA + a] = (short)t;
            if (t >= 0) atomicAdd(&shist[t], 1);
        }
        __syncthreads();
        if (tid < 32) cntChunk[((size_t)b * nCh + ch) * 32 + tid] = shist[tid];
    }
}

// K2: prologue (wave 0, O(1) work only): cnt0 = sum cntChunk; fix1 groups
// (adjust counts + pre-owners, record adds); fix2 32-step register scan
// (record adds); finalize override list -> final tgt per overridden anchor.
// Main pass: t = tgt0 (short load) unless overridden; 1 IoU; gather; writes;
// block-cooperative float4 ts write.
__global__ void k_final(const float* __restrict__ pds, const float4* __restrict__ pdb,
                        const float4* __restrict__ gtb, const int* __restrict__ gtl,
                        const void* mg, int nw,
                        const unsigned long long* __restrict__ colKey,
                        const unsigned char* __restrict__ needByte,
                        const unsigned* __restrict__ rowbits0,
                        const short* __restrict__ tgt0,
                        const int* __restrict__ cntChunk,
                        float* __restrict__ out,
                        int A, int M, int C, int B, int nCh) {
    int b = blockIdx.y;
    int base = blockIdx.x * 256;
    int tid = threadIdx.x;
    int mode = detect_mode(mg, nw);
    size_t bA = (size_t)b * A;
    __shared__ float4 sg[32];
    __shared__ int slab[32];
    __shared__ int ovrA[64];
    __shared__ unsigned ovrAdd[64];
    __shared__ short ovrT[64];
    __shared__ int sNov;
    __shared__ float snorm[256];
    __shared__ int stl[256];
    if (tid < 32) {
        sg[tid]   = (tid < M) ? gtb[b * M + tid] : make_float4(0.f, 0.f, 0.f, 0.f);
        slab[tid] = (tid < M) ? gtl[b * M + tid] : 0;
    }
    __syncthreads();

    if (tid < 64) {
        // ---- lane state (lane g<32 owns gt g) ----
        bool mv = false, needv = false;
        int best = -1, c0 = 0;
        if (tid < M) mv = mask_at(mg, mode, b * M + tid);
        if (mv) {
            unsigned long long key = colKey[b * M + tid];
            best = (int)(0xFFFFFFFFu - (unsigned)(key & 0xFFFFFFFFull));
            needv = (needByte[b * M + tid] != 0);
        }
        if (tid < 32) {
            for (int ch = 0; ch < nCh; ch++)
                c0 += cntChunk[((size_t)b * nCh + ch) * 32 + tid];
        }
        int myPre = (mv && best >= 0) ? (int)tgt0[bA + best] : -1;
        unsigned maskbits = (unsigned)__ballot(mv);
        unsigned needBits = (unsigned)__ballot(needv);
        unsigned myEq = 0u;
        for (int g2 = 0; g2 < 32; g2++) {
            int bb = __shfl(best, g2);
            if (bb == best) myEq |= (1u << g2);
        }
        int nov = 0;
        // ---- fix1: groups of needy gts sharing the same best anchor ----
        unsigned rem = needBits;
        while (rem) {
            int gl = __ffs(rem) - 1;                       // group leader
            unsigned em = __shfl(myEq, gl) & needBits;     // group members
            rem &= ~em;
            int aF = __shfl(best, gl);
            unsigned addb = em;                            // bits added to aF
            unsigned bits1 = rowbits0[bA + aF] | addb;
            int t1;
            if (__popc(bits1) > 1) {
                // select1 recompute: full-row IoU argmax (first-max tiebreak)
                float4 p = pdb[bA + aF];
                unsigned long long kk = 0ull;
                if (tid < M) {
                    float vv = iou_pair(p, sg[tid]);
                    kk = ((unsigned long long)__float_as_uint(vv) << 32) |
                         (0xFFFFFFFFu - (unsigned)tid);
                }
                for (int off = 32; off; off >>= 1) {
                    unsigned long long o = __shfl_down(kk, off);
                    if (o > kk) kk = o;
                }
                kk = __shfl(kk, 0);
                t1 = (int)(0xFFFFFFFFu - (unsigned)(kk & 0xFFFFFFFFull));
            } else {
                t1 = __ffs(bits1) - 1;                     // bits0 was empty
            }
            int t0a = __shfl(myPre, gl);                   // tgt0[aF]
            if (tid == t0a && t0a >= 0) c0--;              // count adjust
            if (tid == t1) c0++;
            if (best == aF) myPre = t1;                    // new pre-owner
            if (tid == 0) { ovrA[nov] = aF; ovrAdd[nov] = addb; }
            nov++;
        }
        // ---- fix2: order-dependent 32-step scan in registers ----
        unsigned applied = 0u;
        for (int g = 0; g < M; g++) {
            int cg = __shfl(c0, g);
            if (((maskbits >> g) & 1u) && cg == 0) {
                int aa      = __shfl(best, g);
                unsigned em = __shfl(myEq, g);
                unsigned x  = applied & em;
                int old;
                if (x) old = 31 - __clz(x);    // last earlier step took this anchor
                else   old = __shfl(myPre, g); // owner after fix1 (-1 = background)
                if (tid == old) c0--;
                if (tid == g)   c0++;
                applied |= (1u << g);
                if (tid == 0) { ovrA[nov] = aa; ovrAdd[nov] = 1u << g; }
                nov++;
            }
        }
        if (tid == 0) sNov = nov;
    }
    __syncthreads();
    // ---- finalize overrides: final tgt per entry (wave 0) ----
    if (tid < 64) {
        int nov2 = sNov;
        for (int j = 0; j < nov2; j++) {
            int aj = ovrA[j];
            unsigned addT = 0u;
            for (int k = 0; k < nov2; k++) if (ovrA[k] == aj) addT |= ovrAdd[k];
            unsigned bt = rowbits0[bA + aj] | addT;
            int tf;
            if (__popc(bt) > 1) {
                float4 p = pdb[bA + aj];
                unsigned long long kk = 0ull;
                if (tid < M) {
                    float vv = iou_pair(p, sg[tid]);
                    kk = ((unsigned long long)__float_as_uint(vv) << 32) |
                         (0xFFFFFFFFu - (unsigned)tid);
                }
                for (int off = 32; off; off >>= 1) {
                    unsigned long long o = __shfl_down(kk, off);
                    if (o > kk) kk = o;
                }
                kk = __shfl(kk, 0);
                tf = (int)(0xFFFFFFFFu - (unsigned)(kk & 0xFFFFFFFFull));
            } else {
                tf = __ffs(bt) - 1;
            }
            if (tid == 0) ovrT[j] = (short)tf;
        }
    }
    __syncthreads();

    // ---- main: per-anchor outputs (no argmax; tgt0 + override list) ----
    int a = base + tid;
    size_t BA = (size_t)B * A;
    if (a < A) {
        size_t idx = bA + a;
        int t = (int)tgt0[idx];
        int nov2 = sNov;
        for (int j = 0; j < nov2; j++)
            if (ovrA[j] == a) t = (int)ovrT[j];
        int fg = (t >= 0);
        int tgtO = fg ? t : 0;
        int lab = slab[tgtO];
        int tl = min(max(lab, 0), C);            // clip(., 0, NUM_CLASSES)
        float norm = 0.0f;
        if (fg) {
            float ov = iou_pair(pdb[idx], sg[t]);
            int li = (lab >= 0 && lab < C) ? lab : 0;
            float cls = pds[idx * (size_t)C + li];
            float ov6 = powf(ov, 6.0f);          // overlaps ** BETA
            float vv = cls * ov6;                // align_metric at (a, tgt)
            norm = vv * ov / (vv + 1e-9f);       // pam*pov/(pam+eps)
        }
        out[idx] = (float)tl;                                // tl
        ((float4*)(out + BA))[idx] = sg[tgtO];               // tb
        out[BA * (size_t)(5 + C) + idx] = fg ? 1.0f : 0.0f;  // fg
        out[BA * (size_t)(6 + C) + idx] = (float)tgtO;       // tgt
        snorm[tid] = norm;
        stl[tid] = tl;
    }
    __syncthreads();
    int cntA = min(256, A - base);
    int rowf4 = C >> 2;
    int nf4 = cntA * rowf4;
    float4* tsb = (float4*)(out + BA * 5 + (bA + base) * C);
    int q = 256 / rowf4, r = 256 - q * rowf4;
    int row = tid / rowf4;
    int c4  = tid - row * rowf4;
    for (int i = tid; i < nf4; i += 256) {
        float nv = snorm[row];
        int tl   = stl[row];
        int cb = c4 * 4;
        float4 vv;
        vv.x = (tl == cb + 0) ? nv : 0.0f;
        vv.y = (tl == cb + 1) ? nv : 0.0f;
        vv.z = (tl == cb + 2) ? nv : 0.0f;
        vv.w = (tl == cb + 3) ? nv : 0.0f;
        tsb[i] = vv;
        row += q; c4 += r;
        if (c4 >= rowf4) { c4 -= rowf4; row++; }
    }
}

extern "C" void kernel_launch(void* const* d_in, const int* in_sizes, int n_in,
                              void* d_out, int out_size, void* d_ws, size_t ws_size,
                              hipStream_t stream) {
    const float*  pd_scores = (const float*)d_in[0];
    const float4* pd_bboxes = (const float4*)d_in[1];
    const float2* anc       = (const float2*)d_in[2];
    const int*    gt_labels = (const int*)d_in[3];
    const float4* gt_bboxes = (const float4*)d_in[4];
    const void*   mask_gt   = d_in[5];

    int A = in_sizes[2] / 2;
    int B = in_sizes[1] / (A * 4);
    int M = in_sizes[3] / B;
    int C = (int)((long long)in_sizes[0] / ((long long)B * A));
    int nCh = (A + 255) / 256;
    int nw = (B * M) / 4; if (nw > 256) nw = 256;

    char* wp = (char*)d_ws;
    auto carve = [&](size_t bytes) -> char* {
        char* r = wp; wp += (bytes + 255) & ~(size_t)255; return r;
    };
    unsigned* rowbits0         = (unsigned*)carve((size_t)B * A * 4);
    short* tgt0                = (short*)carve((size_t)B * A * 2);
    unsigned long long* colKey = (unsigned long long*)carve((size_t)B * M * 8);
    unsigned char* needByte    = (unsigned char*)carve((size_t)B * M);
    int* cntChunk              = (int*)carve((size_t)B * nCh * 32 * 4);

    float* out = (float*)d_out;

    k_phase1<<<dim3(M + nCh, B), 256, 0, stream>>>(pd_bboxes, anc, gt_bboxes, mask_gt, nw,
                                                   colKey, needByte, rowbits0, tgt0,
                                                   cntChunk, A, M, nCh);
    k_final<<<dim3(nCh, B), 256, 0, stream>>>(pd_scores, pd_bboxes, gt_bboxes, gt_labels,
                                              mask_gt, nw, colKey, needByte, rowbits0,
                                              tgt0, cntChunk, out, A, M, C, B, nCh);
}